// Round 2
// baseline (309.212 us; speedup 1.0000x reference)
//
#include <hip/hip_runtime.h>
#include <hip/hip_bf16.h>

#define TEMP_INV 14.285714285714286f  // 1/0.07

typedef __attribute__((ext_vector_type(8))) short bf16x8;
typedef __attribute__((ext_vector_type(4))) float f32x4;

#define ASYNC_COPY16(gp, lp)                                                  \
  __builtin_amdgcn_global_load_lds(                                           \
      (__attribute__((address_space(1))) const void*)(gp),                    \
      (__attribute__((address_space(3))) void*)(lp), 16, 0, 0)

// ---------------- row L2-normalize -> bf16 ----------------
// one wave per row; D == 512 (8 floats/lane)
__global__ __launch_bounds__(256) void norm_k(const float* __restrict__ feat,
                                              ushort* __restrict__ fbf, int N, int D) {
  const int row = (blockIdx.x * 256 + threadIdx.x) >> 6;
  const int lane = threadIdx.x & 63;
  if (row >= N) return;
  const float4* fr = (const float4*)(feat + (size_t)row * D);
  float4 v0 = fr[lane * 2];
  float4 v1 = fr[lane * 2 + 1];
  float ss = v0.x * v0.x + v0.y * v0.y + v0.z * v0.z + v0.w * v0.w +
             v1.x * v1.x + v1.y * v1.y + v1.z * v1.z + v1.w * v1.w;
  #pragma unroll
  for (int off = 32; off; off >>= 1) ss += __shfl_xor(ss, off, 64);
  const float inv = 1.0f / fmaxf(sqrtf(ss), 1e-12f);
  float x[8] = {v0.x, v0.y, v0.z, v0.w, v1.x, v1.y, v1.z, v1.w};
  ushort o[8];
  #pragma unroll
  for (int i = 0; i < 8; i++) {
    __hip_bfloat16 h = __float2bfloat16(x[i] * inv);
    o[i] = *(ushort*)&h;
  }
  *(uint4*)(fbf + (size_t)row * D + lane * 8) = *(uint4*)o;
}

// ---------------- group labels + histogram ----------------
__global__ void label_k(const int* __restrict__ labels, const int* __restrict__ kptr,
                        int* __restrict__ glab, int* __restrict__ cnt, int N) {
  const int k = *kptr;
  const int B = N / k;
  __shared__ int h[64];
  const int t = threadIdx.x;
  if (t < 64) h[t] = 0;
  __syncthreads();
  for (int b = t; b < B; b += blockDim.x) {
    int lb = labels[(size_t)b * k];
    if (lb >= 0 && lb < 64) atomicAdd(&h[lb], 1);
  }
  __syncthreads();
  if (t < 64) cnt[t] = h[t];
  for (int i = t; i < N; i += blockDim.x) glab[i] = labels[(size_t)(i / k) * k];
}

// ---------------- fused GEMM + masked-softmax-stats epilogue ----------------
// 128x128 tile, 4 waves, each wave 64x64 via 4x4 grid of 16x16x32 bf16 MFMA.
// Staging via global_load_lds width=16: wave w stages one 64-row quadrant
// (w0/w1 -> A halves, w2/w3 -> B halves), 4 DMA instrs of 1 KiB each per K-step.
__global__ __launch_bounds__(256) void gemm_k(const ushort* __restrict__ fbf,
                                              const int* __restrict__ glab,
                                              float* __restrict__ rowS,
                                              float* __restrict__ rowP,
                                              int N, int D) {
  __shared__ ushort As[128 * 32];
  __shared__ ushort Bs[128 * 32];
  const int t = threadIdx.x;
  const int lane = t & 63;
  const int wid = t >> 6;
  const int wrow = wid >> 1, wcol = wid & 1;
  const int quad = lane >> 4, l15 = lane & 15;
  const int i0 = blockIdx.y * 128, j0 = blockIdx.x * 128;

  f32x4 acc[4][4];
  #pragma unroll
  for (int mi = 0; mi < 4; mi++)
    #pragma unroll
    for (int ni = 0; ni < 4; ni++) {
      f32x4 z = {0.f, 0.f, 0.f, 0.f};
      acc[mi][ni] = z;
    }

  // staging assignment (per wave): 64 rows starting at rbase of A or B tile
  ushort* sbase = (wid < 2) ? As : Bs;
  const int rbase = (wid & 1) * 64;
  const ushort* gsrc = fbf + (size_t)(((wid < 2) ? i0 : j0) + rbase) * D +
                       (size_t)(lane >> 2) * D + (lane & 3) * 8;
  ushort* ldst = sbase + rbase * 32;

  const int ko = quad * 8;

  for (int kb = 0; kb < D; kb += 32) {
    __syncthreads();
    #pragma unroll
    for (int c = 0; c < 4; c++)
      ASYNC_COPY16(gsrc + kb + (size_t)c * 16 * D, ldst + c * 512);
    __syncthreads();

    bf16x8 a[4], b[4];
    #pragma unroll
    for (int mi = 0; mi < 4; mi++)
      a[mi] = *(const bf16x8*)&As[(wrow * 64 + mi * 16 + l15) * 32 + ko];
    #pragma unroll
    for (int ni = 0; ni < 4; ni++)
      b[ni] = *(const bf16x8*)&Bs[(wcol * 64 + ni * 16 + l15) * 32 + ko];
    #pragma unroll
    for (int mi = 0; mi < 4; mi++)
      #pragma unroll
      for (int ni = 0; ni < 4; ni++)
        acc[mi][ni] = __builtin_amdgcn_mfma_f32_16x16x32_bf16(a[mi], b[ni], acc[mi][ni], 0, 0, 0);
  }

  // epilogue: per-element exp + mask, 16-lane row reduce, atomics
  const int colbase = j0 + wcol * 64 + l15;
  int clab[4];
  #pragma unroll
  for (int ni = 0; ni < 4; ni++) clab[ni] = glab[colbase + ni * 16];

  #pragma unroll
  for (int mi = 0; mi < 4; mi++) {
    #pragma unroll
    for (int r = 0; r < 4; r++) {
      const int row = i0 + wrow * 64 + mi * 16 + quad * 4 + r;
      const int rlab = glab[row];
      float Ssum = 0.f, Psum = 0.f;
      #pragma unroll
      for (int ni = 0; ni < 4; ni++) {
        const int col = colbase + ni * 16;
        const float val = acc[mi][ni][r];
        const float lg = fmaf(val, TEMP_INV, -TEMP_INV);  // (sim - 1)/T
        const bool diag = (row == col);
        const float e = diag ? 0.f : __expf(lg);
        Ssum += e;
        if (!diag && rlab == clab[ni]) Psum += lg;
      }
      #pragma unroll
      for (int off = 8; off; off >>= 1) {
        Ssum += __shfl_xor(Ssum, off, 64);
        Psum += __shfl_xor(Psum, off, 64);
      }
      if (l15 == 0) {
        atomicAdd(&rowS[row], Ssum);
        atomicAdd(&rowP[row], Psum);
      }
    }
  }
}

// ---------------- final loss reduction ----------------
__global__ void loss_k(const float* __restrict__ rowS, const float* __restrict__ rowP,
                       const int* __restrict__ glab, const int* __restrict__ cnt,
                       const int* __restrict__ kptr, float* __restrict__ out, int N) {
  const int k = *kptr;
  const int t = threadIdx.x;
  float lsum = 0.f, vsum = 0.f;
  for (int i = t; i < N; i += blockDim.x) {
    const int np = cnt[glab[i]] * k - 1;
    if (np > 0) {
      const float S = rowS[i] + 1e-8f;
      const float P = rowP[i];
      const float mlp = (P - (float)np * logf(S)) / (float)np;
      lsum += -mlp;  // -(T/BASE_T) = -1
      vsum += 1.f;
    }
  }
  #pragma unroll
  for (int off = 32; off; off >>= 1) {
    lsum += __shfl_xor(lsum, off, 64);
    vsum += __shfl_xor(vsum, off, 64);
  }
  __shared__ float sl[4], sv[4];
  if ((t & 63) == 0) { sl[t >> 6] = lsum; sv[t >> 6] = vsum; }
  __syncthreads();
  if (t == 0) {
    float L = sl[0] + sl[1] + sl[2] + sl[3];
    float V = sv[0] + sv[1] + sv[2] + sv[3];
    out[0] = L / fmaxf(V, 1.f);
  }
}

extern "C" void kernel_launch(void* const* d_in, const int* in_sizes, int n_in,
                              void* d_out, int out_size, void* d_ws, size_t ws_size,
                              hipStream_t stream) {
  const float* feat = (const float*)d_in[0];
  const int* labels = (const int*)d_in[1];
  const int* kptr   = (const int*)d_in[2];
  const int N = in_sizes[1];
  const int D = in_sizes[0] / N;  // 512

  char* ws = (char*)d_ws;
  ushort* fbf = (ushort*)ws;
  size_t off = (size_t)N * D * sizeof(ushort);
  float* rowS = (float*)(ws + off); off += (size_t)N * sizeof(float);
  float* rowP = (float*)(ws + off); off += (size_t)N * sizeof(float);
  int* glab   = (int*)(ws + off);   off += (size_t)N * sizeof(int);
  int* cnt    = (int*)(ws + off);   off += 64 * sizeof(int);

  hipMemsetAsync(rowS, 0, 2 * (size_t)N * sizeof(float), stream);

  norm_k<<<(N + 3) / 4, 256, 0, stream>>>(feat, fbf, N, D);
  label_k<<<1, 256, 0, stream>>>(labels, kptr, glab, cnt, N);
  dim3 grid(N / 128, N / 128);
  gemm_k<<<grid, 256, 0, stream>>>(fbf, glab, rowS, rowP, N, D);
  loss_k<<<1, 256, 0, stream>>>(rowS, rowP, glab, cnt, kptr, (float*)d_out, N);
}

// Round 3
// 267.152 us; speedup vs baseline: 1.1574x; 1.1574x over previous
//
#include <hip/hip_runtime.h>
#include <hip/hip_bf16.h>

#define TEMP_INV 14.285714285714286f  // 1/0.07

typedef __attribute__((ext_vector_type(8))) short bf16x8;
typedef __attribute__((ext_vector_type(4))) float f32x4;

#define ASYNC_COPY16(gp, lp)                                                  \
  __builtin_amdgcn_global_load_lds(                                           \
      (__attribute__((address_space(1))) const void*)(gp),                    \
      (__attribute__((address_space(3))) void*)(lp), 16, 0, 0)

// ---------------- row L2-normalize -> bf16, + labels/histogram on block 0 ----
// one wave per row; D == 512 (8 floats/lane, fully coalesced float4 loads)
__global__ __launch_bounds__(256) void norm_label_k(const float* __restrict__ feat,
                                                    ushort* __restrict__ fbf,
                                                    const int* __restrict__ labels,
                                                    const int* __restrict__ kptr,
                                                    int* __restrict__ glab,
                                                    int* __restrict__ cnt,
                                                    int N, int D) {
  const int row = (blockIdx.x * 256 + threadIdx.x) >> 6;
  const int lane = threadIdx.x & 63;
  if (row < N) {
    const float4* fr = (const float4*)(feat + (size_t)row * D);
    float4 v0 = fr[lane];        // floats 4l .. 4l+3
    float4 v1 = fr[lane + 64];   // floats 256+4l .. 256+4l+3
    float ss = v0.x * v0.x + v0.y * v0.y + v0.z * v0.z + v0.w * v0.w +
               v1.x * v1.x + v1.y * v1.y + v1.z * v1.z + v1.w * v1.w;
    #pragma unroll
    for (int off = 32; off; off >>= 1) ss += __shfl_xor(ss, off, 64);
    const float inv = 1.0f / fmaxf(sqrtf(ss), 1e-12f);
    float x0[4] = {v0.x, v0.y, v0.z, v0.w};
    float x1[4] = {v1.x, v1.y, v1.z, v1.w};
    ushort o0[4], o1[4];
    #pragma unroll
    for (int i = 0; i < 4; i++) {
      __hip_bfloat16 h0 = __float2bfloat16(x0[i] * inv);
      __hip_bfloat16 h1 = __float2bfloat16(x1[i] * inv);
      o0[i] = *(ushort*)&h0;
      o1[i] = *(ushort*)&h1;
    }
    *(uint2*)(fbf + (size_t)row * D + lane * 4)       = *(uint2*)o0;
    *(uint2*)(fbf + (size_t)row * D + 256 + lane * 4) = *(uint2*)o1;
  }
  if (blockIdx.x == 0) {
    const int k = *kptr;
    const int B = N / k;
    __shared__ int h[64];
    const int t = threadIdx.x;
    if (t < 64) h[t] = 0;
    __syncthreads();
    for (int b = t; b < B; b += 256) {
      int lb = labels[(size_t)b * k];
      if (lb >= 0 && lb < 64) atomicAdd(&h[lb], 1);
    }
    __syncthreads();
    if (t < 64) cnt[t] = h[t];
    for (int i = t; i < N; i += 256) glab[i] = labels[(size_t)(i / k) * k];
  }
}

// ---------------- fused GEMM + masked-softmax-stats, upper-triangle only ----
// 128x128 tile, BK=128 (whole K-chunk in LDS, 64 KB), 4 waves, 4x4 frags of
// 16x16x32 bf16 MFMA. LDS chunk-XOR swizzle (chunk ^ row&15) applied via the
// DMA *source* permutation (DMA dest is lane-forced contiguous).
// Off-diagonal blocks (bi<bj) also emit column stats (symmetry).
__global__ __launch_bounds__(256) void gemm_k(const ushort* __restrict__ fbf,
                                              const int* __restrict__ glab,
                                              float* __restrict__ rowS,
                                              float* __restrict__ rowP,
                                              int N, int D) {
  __shared__ ushort As[128 * 128];
  __shared__ ushort Bs[128 * 128];
  const int t = threadIdx.x;
  const int lane = t & 63;
  const int wid = t >> 6;
  const int wrow = wid >> 1, wcol = wid & 1;
  const int quad = lane >> 4, l15 = lane & 15;

  // decode upper-triangle block (bi, bj), bj >= bi
  const int nb = N / 128;
  int idx = blockIdx.x, bi = 0;
  while (idx >= nb - bi) { idx -= nb - bi; bi++; }
  const int bj = bi + idx;
  const int i0 = bi * 128, j0 = bj * 128;
  const bool diagblk = (bi == bj);

  f32x4 acc[4][4];
  #pragma unroll
  for (int mi = 0; mi < 4; mi++)
    #pragma unroll
    for (int ni = 0; ni < 4; ni++) {
      f32x4 z = {0.f, 0.f, 0.f, 0.f};
      acc[mi][ni] = z;
    }

  // staging: wave w stages 64 rows of A (w=0,1) or B (w=2,3)
  ushort* sb = (wid < 2) ? As : Bs;
  const int rbase = (wid & 1) * 64;
  const int rowstart = ((wid < 2) ? i0 : j0) + rbase;
  const int lhi = lane >> 4;   // 0..3: row within 4-row DMA group
  const int lch = lane & 15;   // LDS chunk written by this lane

  for (int kb = 0; kb < D; kb += 128) {
    __syncthreads();
    #pragma unroll
    for (int i = 0; i < 16; i++) {
      const int rl = 4 * i + lhi;               // local row 0..63
      const int cg = lch ^ (rl & 15);           // swizzled global chunk
      ASYNC_COPY16(fbf + (size_t)(rowstart + rl) * D + kb + cg * 8,
                   sb + (rbase + 4 * i) * 128);
    }
    __syncthreads();
    #pragma unroll
    for (int s = 0; s < 4; s++) {
      const int ch = s * 4 + quad;              // logical 16B chunk in row
      bf16x8 a[4], b[4];
      #pragma unroll
      for (int mi = 0; mi < 4; mi++) {
        const int r = wrow * 64 + mi * 16 + l15;  // r&15 == l15
        a[mi] = *(const bf16x8*)&As[r * 128 + ((ch ^ l15) * 8)];
      }
      #pragma unroll
      for (int ni = 0; ni < 4; ni++) {
        const int r = wcol * 64 + ni * 16 + l15;
        b[ni] = *(const bf16x8*)&Bs[r * 128 + ((ch ^ l15) * 8)];
      }
      #pragma unroll
      for (int mi = 0; mi < 4; mi++)
        #pragma unroll
        for (int ni = 0; ni < 4; ni++)
          acc[mi][ni] = __builtin_amdgcn_mfma_f32_16x16x32_bf16(a[mi], b[ni], acc[mi][ni], 0, 0, 0);
    }
  }

  // ---- epilogue ----
  const int colbase = j0 + wcol * 64 + l15;
  int clab[4];
  #pragma unroll
  for (int ni = 0; ni < 4; ni++) clab[ni] = glab[colbase + ni * 16];

  float colE[4] = {0.f, 0.f, 0.f, 0.f};
  float colP[4] = {0.f, 0.f, 0.f, 0.f};

  #pragma unroll
  for (int mi = 0; mi < 4; mi++) {
    const int rowb = i0 + wrow * 64 + mi * 16 + quad * 4;
    #pragma unroll
    for (int r = 0; r < 4; r++) {
      const int row = rowb + r;
      const int rlab = glab[row];
      float Ssum = 0.f, Psum = 0.f;
      #pragma unroll
      for (int ni = 0; ni < 4; ni++) {
        const int col = colbase + ni * 16;
        const float val = acc[mi][ni][r];
        const float lg = fmaf(val, TEMP_INV, -TEMP_INV);  // (sim - 1)/T
        const bool diag = diagblk && (row == col);
        const float e = diag ? 0.f : __expf(lg);
        const float pm = (!diag && rlab == clab[ni]) ? lg : 0.f;
        Ssum += e;
        Psum += pm;
        colE[ni] += e;
        colP[ni] += pm;
      }
      #pragma unroll
      for (int off = 8; off; off >>= 1) {
        Ssum += __shfl_xor(Ssum, off, 64);
        Psum += __shfl_xor(Psum, off, 64);
      }
      if (l15 == 0) {
        atomicAdd(&rowS[row], Ssum);
        atomicAdd(&rowP[row], Psum);
      }
    }
  }

  if (!diagblk) {
    // column stats: sim symmetric, block (bi,bj) also serves rows j0..j0+127
    #pragma unroll
    for (int ni = 0; ni < 4; ni++) {
      float e = colE[ni];
      float p = colP[ni];
      e += __shfl_xor(e, 16, 64);
      e += __shfl_xor(e, 32, 64);
      p += __shfl_xor(p, 16, 64);
      p += __shfl_xor(p, 32, 64);
      if (quad == 0) {
        atomicAdd(&rowS[colbase + ni * 16], e);
        atomicAdd(&rowP[colbase + ni * 16], p);
      }
    }
  }
}

// ---------------- final loss reduction ----------------
__global__ void loss_k(const float* __restrict__ rowS, const float* __restrict__ rowP,
                       const int* __restrict__ glab, const int* __restrict__ cnt,
                       const int* __restrict__ kptr, float* __restrict__ out, int N) {
  const int k = *kptr;
  const int t = threadIdx.x;
  float lsum = 0.f, vsum = 0.f;
  for (int i = t; i < N; i += blockDim.x) {
    const int np = cnt[glab[i]] * k - 1;
    if (np > 0) {
      const float S = rowS[i] + 1e-8f;
      const float P = rowP[i];
      const float mlp = (P - (float)np * logf(S)) / (float)np;
      lsum += -mlp;  // -(T/BASE_T) = -1
      vsum += 1.f;
    }
  }
  #pragma unroll
  for (int off = 32; off; off >>= 1) {
    lsum += __shfl_xor(lsum, off, 64);
    vsum += __shfl_xor(vsum, off, 64);
  }
  __shared__ float sl[4], sv[4];
  if ((t & 63) == 0) { sl[t >> 6] = lsum; sv[t >> 6] = vsum; }
  __syncthreads();
  if (t == 0) {
    float L = sl[0] + sl[1] + sl[2] + sl[3];
    float V = sv[0] + sv[1] + sv[2] + sv[3];
    out[0] = L / fmaxf(V, 1.f);
  }
}

extern "C" void kernel_launch(void* const* d_in, const int* in_sizes, int n_in,
                              void* d_out, int out_size, void* d_ws, size_t ws_size,
                              hipStream_t stream) {
  const float* feat = (const float*)d_in[0];
  const int* labels = (const int*)d_in[1];
  const int* kptr   = (const int*)d_in[2];
  const int N = in_sizes[1];
  const int D = in_sizes[0] / N;  // 512

  char* ws = (char*)d_ws;
  ushort* fbf = (ushort*)ws;
  size_t off = (size_t)N * D * sizeof(ushort);
  float* rowS = (float*)(ws + off); off += (size_t)N * sizeof(float);
  float* rowP = (float*)(ws + off); off += (size_t)N * sizeof(float);
  int* glab   = (int*)(ws + off);   off += (size_t)N * sizeof(int);
  int* cnt    = (int*)(ws + off);   off += 64 * sizeof(int);

  hipMemsetAsync(rowS, 0, 2 * (size_t)N * sizeof(float), stream);

  norm_label_k<<<(N + 3) / 4, 256, 0, stream>>>(feat, fbf, labels, kptr, glab, cnt, N, D);
  const int nb = N / 128;
  gemm_k<<<nb * (nb + 1) / 2, 256, 0, stream>>>(fbf, glab, rowS, rowP, N, D);
  loss_k<<<1, 256, 0, stream>>>(rowS, rowP, glab, cnt, kptr, (float*)d_out, N);
}

// Round 4
// 178.473 us; speedup vs baseline: 1.7325x; 1.4969x over previous
//
#include <hip/hip_runtime.h>
#include <hip/hip_bf16.h>

#define TEMP_INV 14.285714285714286f  // 1/0.07

typedef __attribute__((ext_vector_type(8))) short bf16x8;
typedef __attribute__((ext_vector_type(4))) float f32x4;

#define ASYNC_COPY16(gp, lp)                                                  \
  __builtin_amdgcn_global_load_lds(                                           \
      (__attribute__((address_space(1))) const void*)(gp),                    \
      (__attribute__((address_space(3))) void*)(lp), 16, 0, 0)

// ---- row L2-normalize -> bf16, + labels/histogram (block 0) + zero rowS/rowP
__global__ __launch_bounds__(256) void norm_label_k(const float* __restrict__ feat,
                                                    ushort* __restrict__ fbf,
                                                    const int* __restrict__ labels,
                                                    const int* __restrict__ kptr,
                                                    int* __restrict__ glab,
                                                    int* __restrict__ cnt,
                                                    float* __restrict__ zbuf,
                                                    int N, int D) {
  // zero rowS/rowP (2N floats, contiguous at zbuf)
  const int zi = blockIdx.x * 256 + threadIdx.x;
  if (zi < 2 * N) zbuf[zi] = 0.f;

  const int row = (blockIdx.x * 256 + threadIdx.x) >> 6;
  const int lane = threadIdx.x & 63;
  if (row < N) {
    const float4* fr = (const float4*)(feat + (size_t)row * D);
    float4 v0 = fr[lane];
    float4 v1 = fr[lane + 64];
    float ss = v0.x * v0.x + v0.y * v0.y + v0.z * v0.z + v0.w * v0.w +
               v1.x * v1.x + v1.y * v1.y + v1.z * v1.z + v1.w * v1.w;
    #pragma unroll
    for (int off = 32; off; off >>= 1) ss += __shfl_xor(ss, off, 64);
    const float inv = 1.0f / fmaxf(sqrtf(ss), 1e-12f);
    float x0[4] = {v0.x, v0.y, v0.z, v0.w};
    float x1[4] = {v1.x, v1.y, v1.z, v1.w};
    ushort o0[4], o1[4];
    #pragma unroll
    for (int i = 0; i < 4; i++) {
      __hip_bfloat16 h0 = __float2bfloat16(x0[i] * inv);
      __hip_bfloat16 h1 = __float2bfloat16(x1[i] * inv);
      o0[i] = *(ushort*)&h0;
      o1[i] = *(ushort*)&h1;
    }
    *(uint2*)(fbf + (size_t)row * D + lane * 4)       = *(uint2*)o0;
    *(uint2*)(fbf + (size_t)row * D + 256 + lane * 4) = *(uint2*)o1;
  }
  if (blockIdx.x == 0) {
    const int k = *kptr;
    const int B = N / k;
    __shared__ int h[64];
    const int t = threadIdx.x;
    if (t < 64) h[t] = 0;
    __syncthreads();
    for (int b = t; b < B; b += 256) {
      int lb = labels[(size_t)b * k];
      if (lb >= 0 && lb < 64) atomicAdd(&h[lb], 1);
    }
    __syncthreads();
    if (t < 64) cnt[t] = h[t];
    for (int i = t; i < N; i += 256) glab[i] = labels[(size_t)(i / k) * k];
  }
}

// ---- fused GEMM + masked-softmax-stats, upper-triangle blocks only ----
// 128x128 tile, BK=64 (32 KB LDS single-buffer), 4 waves, 4x4 frags of
// 16x16x32 bf16 MFMA. LDS chunk-XOR swizzle (chunk ^ row&7) applied via the
// DMA source permutation: ds_read_b128 is 2-way on banks (free).
// Off-diagonal blocks (bi<bj) also emit column stats (sim symmetric).
__global__ __launch_bounds__(256, 4) void gemm_k(const ushort* __restrict__ fbf,
                                                 const int* __restrict__ glab,
                                                 float* __restrict__ rowS,
                                                 float* __restrict__ rowP,
                                                 int N, int D) {
  __shared__ ushort As[128 * 64];
  __shared__ ushort Bs[128 * 64];
  const int t = threadIdx.x;
  const int lane = t & 63;
  const int wid = t >> 6;
  const int wrow = wid >> 1, wcol = wid & 1;
  const int quad = lane >> 4, l15 = lane & 15;

  // decode upper-triangle block (bi, bj), bj >= bi
  const int nb = N / 128;
  int idx = blockIdx.x, bi = 0;
  while (idx >= nb - bi) { idx -= nb - bi; bi++; }
  const int bj = bi + idx;
  const int i0 = bi * 128, j0 = bj * 128;
  const bool diagblk = (bi == bj);

  f32x4 acc[4][4];
  #pragma unroll
  for (int mi = 0; mi < 4; mi++)
    #pragma unroll
    for (int ni = 0; ni < 4; ni++) {
      f32x4 z = {0.f, 0.f, 0.f, 0.f};
      acc[mi][ni] = z;
    }

  // staging: wave w stages 64 rows (8 DMAs x 8 rows) of A (w<2) or B (w>=2)
  ushort* sb = (wid < 2) ? As : Bs;
  const int rbase = (wid & 1) * 64;
  const int rowstart = ((wid < 2) ? i0 : j0) + rbase;
  const int lrow = lane >> 3;  // 0..7 row within DMA group
  const int lch = lane & 7;    // LDS slot written by this lane

  for (int kb = 0; kb < D; kb += 64) {
    __syncthreads();
    #pragma unroll
    for (int i = 0; i < 8; i++) {
      const int rl = 8 * i + lrow;
      const int cg = lch ^ (rl & 7);  // swizzled source chunk
      ASYNC_COPY16(fbf + (size_t)(rowstart + rl) * D + kb + cg * 8,
                   sb + (rbase + 8 * i) * 64);
    }
    __syncthreads();
    #pragma unroll
    for (int s = 0; s < 2; s++) {
      const int ch = s * 4 + quad;  // logical 16B chunk within 128B row
      bf16x8 a[4], b[4];
      #pragma unroll
      for (int mi = 0; mi < 4; mi++) {
        const int r = wrow * 64 + mi * 16 + l15;
        a[mi] = *(const bf16x8*)&As[r * 64 + ((ch ^ (r & 7)) * 8)];
      }
      #pragma unroll
      for (int ni = 0; ni < 4; ni++) {
        const int r = wcol * 64 + ni * 16 + l15;
        b[ni] = *(const bf16x8*)&Bs[r * 64 + ((ch ^ (r & 7)) * 8)];
      }
      #pragma unroll
      for (int mi = 0; mi < 4; mi++)
        #pragma unroll
        for (int ni = 0; ni < 4; ni++)
          acc[mi][ni] = __builtin_amdgcn_mfma_f32_16x16x32_bf16(a[mi], b[ni], acc[mi][ni], 0, 0, 0);
    }
  }

  // ---- epilogue ----
  const int colbase = j0 + wcol * 64 + l15;
  int clab[4];
  #pragma unroll
  for (int ni = 0; ni < 4; ni++) clab[ni] = glab[colbase + ni * 16];

  float colE[4] = {0.f, 0.f, 0.f, 0.f};
  float colP[4] = {0.f, 0.f, 0.f, 0.f};

  #pragma unroll
  for (int mi = 0; mi < 4; mi++) {
    const int rowb = i0 + wrow * 64 + mi * 16 + quad * 4;
    #pragma unroll
    for (int r = 0; r < 4; r++) {
      const int row = rowb + r;
      const int rlab = glab[row];
      float Ssum = 0.f, Psum = 0.f;
      #pragma unroll
      for (int ni = 0; ni < 4; ni++) {
        const int col = colbase + ni * 16;
        const float val = acc[mi][ni][r];
        const float lg = fmaf(val, TEMP_INV, -TEMP_INV);  // (sim - 1)/T
        const bool diag = diagblk && (row == col);
        const float e = diag ? 0.f : __expf(lg);
        const float pm = (!diag && rlab == clab[ni]) ? lg : 0.f;
        Ssum += e;
        Psum += pm;
        colE[ni] += e;
        colP[ni] += pm;
      }
      #pragma unroll
      for (int off = 8; off; off >>= 1) {
        Ssum += __shfl_xor(Ssum, off, 64);
        Psum += __shfl_xor(Psum, off, 64);
      }
      if (l15 == 0) {
        atomicAdd(&rowS[row], Ssum);
        atomicAdd(&rowP[row], Psum);
      }
    }
  }

  if (!diagblk) {
    #pragma unroll
    for (int ni = 0; ni < 4; ni++) {
      float e = colE[ni];
      float p = colP[ni];
      e += __shfl_xor(e, 16, 64);
      e += __shfl_xor(e, 32, 64);
      p += __shfl_xor(p, 16, 64);
      p += __shfl_xor(p, 32, 64);
      if (quad == 0) {
        atomicAdd(&rowS[colbase + ni * 16], e);
        atomicAdd(&rowP[colbase + ni * 16], p);
      }
    }
  }
}

// ---------------- final loss reduction ----------------
__global__ __launch_bounds__(1024) void loss_k(const float* __restrict__ rowS,
                                               const float* __restrict__ rowP,
                                               const int* __restrict__ glab,
                                               const int* __restrict__ cnt,
                                               const int* __restrict__ kptr,
                                               float* __restrict__ out, int N) {
  const int k = *kptr;
  const int t = threadIdx.x;
  float lsum = 0.f, vsum = 0.f;
  for (int i = t; i < N; i += 1024) {
    const int np = cnt[glab[i]] * k - 1;
    if (np > 0) {
      const float S = rowS[i] + 1e-8f;
      const float P = rowP[i];
      lsum += -(P - (float)np * logf(S)) / (float)np;
      vsum += 1.f;
    }
  }
  #pragma unroll
  for (int off = 32; off; off >>= 1) {
    lsum += __shfl_xor(lsum, off, 64);
    vsum += __shfl_xor(vsum, off, 64);
  }
  __shared__ float sl[16], sv[16];
  if ((t & 63) == 0) { sl[t >> 6] = lsum; sv[t >> 6] = vsum; }
  __syncthreads();
  if (t == 0) {
    float L = 0.f, V = 0.f;
    #pragma unroll
    for (int i = 0; i < 16; i++) { L += sl[i]; V += sv[i]; }
    out[0] = L / fmaxf(V, 1.f);
  }
}

extern "C" void kernel_launch(void* const* d_in, const int* in_sizes, int n_in,
                              void* d_out, int out_size, void* d_ws, size_t ws_size,
                              hipStream_t stream) {
  const float* feat = (const float*)d_in[0];
  const int* labels = (const int*)d_in[1];
  const int* kptr   = (const int*)d_in[2];
  const int N = in_sizes[1];
  const int D = in_sizes[0] / N;  // 512

  char* ws = (char*)d_ws;
  ushort* fbf = (ushort*)ws;
  size_t off = (size_t)N * D * sizeof(ushort);
  float* rowS = (float*)(ws + off); off += (size_t)N * sizeof(float);
  float* rowP = (float*)(ws + off); off += (size_t)N * sizeof(float);
  int* glab   = (int*)(ws + off);   off += (size_t)N * sizeof(int);
  int* cnt    = (int*)(ws + off);   off += 64 * sizeof(int);

  norm_label_k<<<(N + 3) / 4, 256, 0, stream>>>(feat, fbf, labels, kptr, glab, cnt,
                                                rowS, N, D);
  const int nb = N / 128;
  gemm_k<<<nb * (nb + 1) / 2, 256, 0, stream>>>(fbf, glab, rowS, rowP, N, D);
  loss_k<<<1, 1024, 0, stream>>>(rowS, rowP, glab, cnt, kptr, (float*)d_out, N);
}